// Round 5
// baseline (947.051 us; speedup 1.0000x reference)
//
#include <hip/hip_runtime.h>

typedef unsigned short u16;
typedef unsigned int u32;
typedef __attribute__((ext_vector_type(4))) float f32x4;
typedef __attribute__((ext_vector_type(8))) short bf16x8;
typedef __attribute__((ext_vector_type(2))) unsigned int u32x2;

#define S_LEN 2048
#define NHEAD 32
#define HDD 128
#define HID 4096
#define N_QKV 12288
#define KDIM 4096
#define RS 12288  // mixed row stride (elements)

__device__ __forceinline__ u16 f2bf(float f) {
  u32 u = __builtin_bit_cast(u32, f);
  u = (u + 0x7FFFu + ((u >> 16) & 1u)) >> 16;
  return (u16)u;
}
__device__ __forceinline__ float bf2f(u16 h) {
  u32 u = ((u32)h) << 16;
  return __builtin_bit_cast(float, u);
}

// ---------------- fused fp32 -> bf16 conversion (3 tensors) ---------------
__global__ __launch_bounds__(256) void cvt3_kernel(const float* __restrict__ s0, u16* __restrict__ d0, int n0,
                                                   const float* __restrict__ s1, u16* __restrict__ d1, int n1,
                                                   const float* __restrict__ s2, u16* __restrict__ d2, int n2) {
  int i = blockIdx.x * blockDim.x + threadIdx.x;
  int st = gridDim.x * blockDim.x;
  int ntot = n0 + n1 + n2;
  for (; i < ntot; i += st) {
    const float* s;
    u16* d;
    int j = i;
    if (j < n0) {
      s = s0; d = d0;
    } else if (j < n0 + n1) {
      j -= n0; s = s1; d = d1;
    } else {
      j -= n0 + n1; s = s2; d = d2;
    }
    float4 v = ((const float4*)s)[j];
    u32x2 o;
    o.x = (u32)f2bf(v.x) | ((u32)f2bf(v.y) << 16);
    o.y = (u32)f2bf(v.z) | ((u32)f2bf(v.w) << 16);
    ((u32x2*)d)[j] = o;
  }
}

// ---------------- RoPE tables: cos/sin [S][32] ----------------
__global__ __launch_bounds__(256) void tables_kernel(float* __restrict__ cos_t,
                                                     float* __restrict__ sin_t) {
  int idx = blockIdx.x * blockDim.x + threadIdx.x;
  if (idx >= S_LEN * 32) return;
  int s = idx >> 5, i = idx & 31;
  float invf = expf(-0.28782313662425572f * (float)i);
  float a = (float)s * invf;
  cos_t[idx] = cosf(a);
  sin_t[idx] = sinf(a);
}

// ---------------- 2D RoPE in-place on mixed [s][12288] --------------------
__global__ __launch_bounds__(256) void rope_kernel(u16* __restrict__ mixed,
                                                   const int* __restrict__ pid,
                                                   const float* __restrict__ cos_t,
                                                   const float* __restrict__ sin_t) {
  int idx = blockIdx.x * blockDim.x + threadIdx.x;
  const int total = 2 * NHEAD * S_LEN * 2 * 8;  // 2^21
  if (idx >= total) return;
  int j = idx & 7;
  int half = (idx >> 3) & 1;
  int s = (idx >> 4) & (S_LEN - 1);
  int h = (idx >> 15) & (NHEAD - 1);
  int qk = idx >> 20;
  int i0 = j * 4;
  int p = pid[half * S_LEN + s];
  float4 c4 = *(const float4*)(cos_t + p * 32 + i0);
  float4 s4 = *(const float4*)(sin_t + p * 32 + i0);
  u16* base = mixed + (size_t)s * RS + h * 384 + qk * 128 + half * 64 + i0;
  ushort4 x1v = *(const ushort4*)(base);
  ushort4 x2v = *(const ushort4*)(base + 32);
  float sc = qk ? 1.0f : 0.08838834764831845f;
  ushort4 o1, o2;
  {
    float x1 = bf2f(x1v.x), x2 = bf2f(x2v.x);
    o1.x = f2bf((x1 * c4.x - x2 * s4.x) * sc);
    o2.x = f2bf((x2 * c4.x + x1 * s4.x) * sc);
  }
  {
    float x1 = bf2f(x1v.y), x2 = bf2f(x2v.y);
    o1.y = f2bf((x1 * c4.y - x2 * s4.y) * sc);
    o2.y = f2bf((x2 * c4.y + x1 * s4.y) * sc);
  }
  {
    float x1 = bf2f(x1v.z), x2 = bf2f(x2v.z);
    o1.z = f2bf((x1 * c4.z - x2 * s4.z) * sc);
    o2.z = f2bf((x2 * c4.z + x1 * s4.z) * sc);
  }
  {
    float x1 = bf2f(x1v.w), x2 = bf2f(x2v.w);
    o1.w = f2bf((x1 * c4.w - x2 * s4.w) * sc);
    o2.w = f2bf((x2 * c4.w + x1 * s4.w) * sc);
  }
  *(ushort4*)(base) = o1;
  *(ushort4*)(base + 32) = o2;
}

// ---------------- 256x256 GEMM: A in registers, B-only LDS ring-2 ---------
// C = A * B^T (+bias).  A:[M][4096] bf16, B:[N][4096] bf16.
// 512 thr = 8 waves (2M x 4N), per-wave 128x64, BK=32, 32 MFMA/tile/wave.
// A frags: global->reg double-buffer (wave-private rows, no LDS).
// B tile:  global->reg->LDS (swizzled paired-row layout), ring-2 x 16KB.
// One __syncthreads per K-tile. 32KB LDS -> multiple blocks/CU break the
// phase-lockstep that capped MfmaUtil at ~37% (R2-R4).
// Split-K via blockIdx.y (k0 = y*2048), outf += y*M*N.
template <int EPI>
__global__ __launch_bounds__(512, 2) void gemmRS(const u16* __restrict__ A,
                                                 const u16* __restrict__ B,
                                                 const float* __restrict__ bias, int N, int NTt,
                                                 u16* __restrict__ outb, float* __restrict__ outf) {
  __shared__ __align__(16) char lds[2][16384];

  const int tid = threadIdx.x;
  const int lane = tid & 63, w = tid >> 6;
  const int l15 = lane & 15, g = lane >> 4;
  const int wm = w >> 2, wn = w & 3;

  // bijective XCD swizzle (gridDim.x = 8*perx, perx = 8*npx), M-fastest
  int perx = gridDim.x >> 3;
  int npx = perx >> 3;
  int x = blockIdx.x & 7, loc = blockIdx.x >> 3;
  int mb = loc & 7, nb = x * npx + (loc >> 3);
  const int bm = mb * 256, bn = nb * 256;

  const u16* Ag = A + (size_t)blockIdx.y * 2048;
  const u16* Bg = B + (size_t)blockIdx.y * 2048;

  f32x4 acc[8][4];
  f32x4 z4 = {0.f, 0.f, 0.f, 0.f};
#pragma unroll
  for (int mi = 0; mi < 8; ++mi)
#pragma unroll
    for (int ni = 0; ni < 4; ++ni) acc[mi][ni] = z4;

  // A frag source: lane reads row bm + wm*128 + mi*16 + l15, 16B at g*8 elems
  const u16* aptr = Ag + (size_t)(bm + wm * 128 + l15) * KDIM + g * 8;

  // B staging: thread t covers row = t>>1, 32B chunk at (t&1)*16 elems
  const int brow = tid >> 1;
  const u16* bptr = Bg + (size_t)(bn + brow) * KDIM + (tid & 1) * 16;
  int bwoff[2];
  {
    int line = brow >> 1;
#pragma unroll
    for (int c = 0; c < 2; ++c) {
      int s0 = (brow & 1) * 4 + (tid & 1) * 2 + c;
      int phys = s0 ^ (line & 7);
      bwoff[c] = line * 128 + phys * 16;
    }
  }
  // B frag ds_read offsets (same swizzle)
  int offB[4];
#pragma unroll
  for (int ni = 0; ni < 4; ++ni) {
    int r = wn * 64 + ni * 16 + l15;
    int line = r >> 1;
    int sl = (((r & 1) << 2) + g) ^ (line & 7);
    offB[ni] = line * 128 + sl * 16;
  }

  bf16x8 aA[8], aB[8], bsA[2], bsB[2];

  // ---- prologue: B(0) -> lds0; B(1) -> bsA; A(0) -> aA
  bsA[0] = *(const bf16x8*)(bptr);
  bsA[1] = *(const bf16x8*)(bptr + 8);
  *(bf16x8*)(lds[0] + bwoff[0]) = bsA[0];
  *(bf16x8*)(lds[0] + bwoff[1]) = bsA[1];
  bsA[0] = *(const bf16x8*)(bptr + 32);
  bsA[1] = *(const bf16x8*)(bptr + 40);
#pragma unroll
  for (int mi = 0; mi < 8; ++mi)
    aA[mi] = *(const bf16x8*)(aptr + (size_t)mi * 16 * KDIM);
  __syncthreads();

  for (int kt = 0; kt < NTt; kt += 2) {
    // ---- body A: tile kt (lds0); bsA=B(kt+1), aA=A(kt)
    {
      *(bf16x8*)(lds[1] + bwoff[0]) = bsA[0];
      *(bf16x8*)(lds[1] + bwoff[1]) = bsA[1];
      int t2 = (kt + 2 < NTt) ? kt + 2 : 0;
      bsB[0] = *(const bf16x8*)(bptr + t2 * 32);
      bsB[1] = *(const bf16x8*)(bptr + t2 * 32 + 8);
      int t1 = (kt + 1 < NTt) ? kt + 1 : 0;
#pragma unroll
      for (int mi = 0; mi < 8; ++mi)
        aB[mi] = *(const bf16x8*)(aptr + (size_t)mi * 16 * KDIM + t1 * 32);
      bf16x8 bf_[4];
#pragma unroll
      for (int ni = 0; ni < 4; ++ni) bf_[ni] = *(const bf16x8*)(lds[0] + offB[ni]);
      __builtin_amdgcn_s_setprio(1);
#pragma unroll
      for (int mi = 0; mi < 8; ++mi)
#pragma unroll
        for (int ni = 0; ni < 4; ++ni)
          acc[mi][ni] = __builtin_amdgcn_mfma_f32_16x16x32_bf16(aA[mi], bf_[ni], acc[mi][ni], 0, 0, 0);
      __builtin_amdgcn_s_setprio(0);
      __syncthreads();
    }
    // ---- body B: tile kt+1 (lds1); bsB=B(kt+2), aB=A(kt+1)
    {
      *(bf16x8*)(lds[0] + bwoff[0]) = bsB[0];
      *(bf16x8*)(lds[0] + bwoff[1]) = bsB[1];
      int t3 = (kt + 3 < NTt) ? kt + 3 : 0;
      bsA[0] = *(const bf16x8*)(bptr + t3 * 32);
      bsA[1] = *(const bf16x8*)(bptr + t3 * 32 + 8);
      int t2 = (kt + 2 < NTt) ? kt + 2 : 0;
#pragma unroll
      for (int mi = 0; mi < 8; ++mi)
        aA[mi] = *(const bf16x8*)(aptr + (size_t)mi * 16 * KDIM + t2 * 32);
      bf16x8 bf_[4];
#pragma unroll
      for (int ni = 0; ni < 4; ++ni) bf_[ni] = *(const bf16x8*)(lds[1] + offB[ni]);
      __builtin_amdgcn_s_setprio(1);
#pragma unroll
      for (int mi = 0; mi < 8; ++mi)
#pragma unroll
        for (int ni = 0; ni < 4; ++ni)
          acc[mi][ni] = __builtin_amdgcn_mfma_f32_16x16x32_bf16(aB[mi], bf_[ni], acc[mi][ni], 0, 0, 0);
      __builtin_amdgcn_s_setprio(0);
      __syncthreads();
    }
  }

  // ---- epilogue: D row(M) = 4*g + reg, col(N) = l15
  float* of = outf ? outf + (size_t)blockIdx.y * S_LEN * N : nullptr;
#pragma unroll
  for (int ni = 0; ni < 4; ++ni) {
    int n = bn + wn * 64 + ni * 16 + l15;
    if (EPI == 0) {
      float bv = bias[n];
#pragma unroll
      for (int mi = 0; mi < 8; ++mi) {
        int m0 = bm + wm * 128 + mi * 16 + 4 * g;
#pragma unroll
        for (int rr = 0; rr < 4; ++rr)
          outb[(size_t)(m0 + rr) * N + n] = f2bf(acc[mi][ni][rr] + bv);
      }
    } else {
#pragma unroll
      for (int mi = 0; mi < 8; ++mi) {
        int m0 = bm + wm * 128 + mi * 16 + 4 * g;
#pragma unroll
        for (int rr = 0; rr < 4; ++rr) of[(size_t)(m0 + rr) * N + n] = acc[mi][ni][rr];
      }
    }
  }
}

// ---------------- split-K reduce: out = P0 + P1 + bias --------------------
__global__ __launch_bounds__(256) void reduce_kernel(const float* __restrict__ P0,
                                                     const float* __restrict__ P1,
                                                     const float* __restrict__ bias,
                                                     float* __restrict__ out, int n4) {
  int i = blockIdx.x * blockDim.x + threadIdx.x;
  int st = gridDim.x * blockDim.x;
  for (; i < n4; i += st) {
    float4 a = ((const float4*)P0)[i];
    float4 b = ((const float4*)P1)[i];
    float4 bv = *(const float4*)(bias + ((i * 4) & (HID - 1)));
    float4 o;
    o.x = a.x + b.x + bv.x;
    o.y = a.y + b.y + bv.y;
    o.z = a.z + b.z + bv.z;
    o.w = a.w + b.w + bv.w;
    ((float4*)out)[i] = o;
  }
}

// ---------------- flash attention (reads mixed layout) --------------------
__global__ __launch_bounds__(256) void attn_kernel(const u16* __restrict__ mixed,
                                                   u16* __restrict__ ctx) {
  __shared__ __align__(16) u16 Ksh[32 * 136];
  __shared__ __align__(16) u16 Vsh[128 * 32];
  __shared__ __align__(16) u16 Pt[4][16 * 40];

  int tid = threadIdx.x;
  int lane = tid & 63, w = tid >> 6;
  int lane15 = lane & 15, g = lane >> 4;
  int h = blockIdx.y;
  int qbase = blockIdx.x * 64;
  int qrow = qbase + w * 16 + lane15;

  const u16* qp = mixed + (size_t)h * 384;
  const u16* kp = mixed + (size_t)h * 384 + 128;
  const u16* vp = mixed + (size_t)h * 384 + 256;

  bf16x8 qf[4];
  const u16* qptr = qp + (size_t)qrow * RS + g * 8;
#pragma unroll
  for (int d0 = 0; d0 < 4; ++d0) qf[d0] = *(const bf16x8*)(qptr + d0 * 32);

  f32x4 pv[8];
  f32x4 z4 = {0.f, 0.f, 0.f, 0.f};
#pragma unroll
  for (int db = 0; db < 8; ++db) pv[db] = z4;
  float m_run = -1e30f, l_run = 0.0f;

  int krow = tid >> 3, kc = (tid & 7) * 16;
  int a_ = tid & 15, b_ = tid >> 4;
  int ntiles = (qbase >> 5) + 2;

  for (int t = 0; t < ntiles; ++t) {
    int kb0 = t * 32;
    __syncthreads();
    {
      const bf16x8* src = (const bf16x8*)(kp + (size_t)(kb0 + krow) * RS + kc);
      bf16x8 x0 = src[0], x1 = src[1];
      *(bf16x8*)(Ksh + krow * 136 + kc) = x0;
      *(bf16x8*)(Ksh + krow * 136 + kc + 8) = x1;
      int k0 = 2 * a_, d0 = 8 * b_;
      bf16x8 r0 = *(const bf16x8*)(vp + (size_t)(kb0 + k0) * RS + d0);
      bf16x8 r1 = *(const bf16x8*)(vp + (size_t)(kb0 + k0 + 1) * RS + d0);
#pragma unroll
      for (int jj = 0; jj < 8; ++jj) {
        int d = d0 + jj;
        u32 val = (u32)(u16)r0[jj] | ((u32)(u16)r1[jj] << 16);
        *(u32*)(Vsh + d * 32 + (((k0 >> 3) ^ (d & 3)) << 3) + (k0 & 7)) = val;
      }
    }
    __syncthreads();

    f32x4 sa0 = z4, sa1 = z4;
#pragma unroll
    for (int d0 = 0; d0 < 4; ++d0) {
      bf16x8 k0f = *(const bf16x8*)(Ksh + lane15 * 136 + d0 * 32 + g * 8);
      bf16x8 k1f = *(const bf16x8*)(Ksh + (16 + lane15) * 136 + d0 * 32 + g * 8);
      sa0 = __builtin_amdgcn_mfma_f32_16x16x32_bf16(k0f, qf[d0], sa0, 0, 0, 0);
      sa1 = __builtin_amdgcn_mfma_f32_16x16x32_bf16(k1f, qf[d0], sa1, 0, 0, 0);
    }
    float s[8];
#pragma unroll
    for (int rr = 0; rr < 4; ++rr) {
      int kg0 = kb0 + 4 * g + rr;
      int kg1 = kb0 + 16 + 4 * g + rr;
      s[rr] = (kg0 > qrow) ? -1e30f : sa0[rr];
      s[4 + rr] = (kg1 > qrow) ? -1e30f : sa1[rr];
    }
    float mx = s[0];
#pragma unroll
    for (int i = 1; i < 8; ++i) mx = fmaxf(mx, s[i]);
    mx = fmaxf(mx, __shfl_xor(mx, 16));
    mx = fmaxf(mx, __shfl_xor(mx, 32));
    float mnew = fmaxf(m_run, mx);
    float fac = exp2f((m_run - mnew) * 1.4426950408889634f);
    float p[8], psum = 0.f;
#pragma unroll
    for (int i = 0; i < 8; ++i) {
      p[i] = exp2f((s[i] - mnew) * 1.4426950408889634f);
      psum += p[i];
    }
    psum += __shfl_xor(psum, 16);
    psum += __shfl_xor(psum, 32);
    l_run = l_run * fac + psum;
    m_run = mnew;
#pragma unroll
    for (int db = 0; db < 8; ++db) pv[db] *= fac;

    u32 w0 = (u32)f2bf(p[0]) | ((u32)f2bf(p[1]) << 16);
    u32 w1 = (u32)f2bf(p[2]) | ((u32)f2bf(p[3]) << 16);
    u32 w2 = (u32)f2bf(p[4]) | ((u32)f2bf(p[5]) << 16);
    u32 w3 = (u32)f2bf(p[6]) | ((u32)f2bf(p[7]) << 16);
    u32x2 pa, pb;
    pa.x = w0; pa.y = w1; pb.x = w2; pb.y = w3;
    *(u32x2*)(&Pt[w][lane15 * 40 + 4 * g]) = pa;
    *(u32x2*)(&Pt[w][lane15 * 40 + 16 + 4 * g]) = pb;
    asm volatile("s_waitcnt lgkmcnt(0)" ::: "memory");
    bf16x8 pfrag = *(const bf16x8*)(&Pt[w][lane15 * 40 + 8 * g]);

#pragma unroll
    for (int db = 0; db < 8; ++db) {
      int d = db * 16 + lane15;
      bf16x8 vf = *(const bf16x8*)(Vsh + d * 32 + ((g ^ (d & 3)) << 3));
      pv[db] = __builtin_amdgcn_mfma_f32_16x16x32_bf16(vf, pfrag, pv[db], 0, 0, 0);
    }
  }

  float inv = 1.0f / l_run;
#pragma unroll
  for (int db = 0; db < 8; ++db) {
    ushort4 o;
    o.x = f2bf(pv[db][0] * inv);
    o.y = f2bf(pv[db][1] * inv);
    o.z = f2bf(pv[db][2] * inv);
    o.w = f2bf(pv[db][3] * inv);
    *(ushort4*)(ctx + (size_t)qrow * HID + h * HDD + db * 16 + 4 * g) = o;
  }
}

// ---------------- launcher -------------------------------------------------
extern "C" void kernel_launch(void* const* d_in, const int* in_sizes, int n_in,
                              void* d_out, int out_size, void* d_ws, size_t ws_size,
                              hipStream_t stream) {
  const float* hidden = (const float*)d_in[0];
  const int* pid = (const int*)d_in[1];
  const float* wqkv = (const float*)d_in[3];
  const float* bqkv = (const float*)d_in[4];
  const float* wdense = (const float*)d_in[5];
  const float* bdense = (const float*)d_in[6];
  float* out = (float*)d_out;

  char* ws = (char*)d_ws;
  u16* W1 = (u16*)ws;                        // [12288][4096] bf16 (dead after QKV)
  u16* W2 = (u16*)(ws + 100663296);          // [4096][4096] bf16
  u16* X = (u16*)(ws + 134217728);           // [2048][4096] bf16
  u16* mixed = (u16*)(ws + 150994944);       // [2048][12288] bf16
  u16* ctx = (u16*)(ws + 201326592);         // [2048][4096] bf16
  float* cos_t = (float*)(ws + 218103808);
  float* sin_t = (float*)(ws + 218365952);
  float* P = (float*)ws;                     // split-K partials reuse W1 region
                                             // P0 = P, P1 = P + 2048*4096

  cvt3_kernel<<<dim3(2048), dim3(256), 0, stream>>>(
      wqkv, W1, N_QKV * KDIM / 4, wdense, W2, HID * KDIM / 4, hidden, X, S_LEN * HID / 4);
  tables_kernel<<<dim3(256), dim3(256), 0, stream>>>(cos_t, sin_t);

  // QKV: 8 M x 48 N = 384 blocks, NTt = 128 (full K)
  gemmRS<0><<<dim3(384), dim3(512), 0, stream>>>(
      X, W1, bqkv, N_QKV, 128, mixed, nullptr);

  rope_kernel<<<dim3(8192), dim3(256), 0, stream>>>(mixed, pid, cos_t, sin_t);

  attn_kernel<<<dim3(S_LEN / 64, NHEAD), dim3(256), 0, stream>>>(mixed, ctx);

  // dense: split-K x2 in ONE launch (blockIdx.y = k-half), 256 blocks total
  gemmRS<1><<<dim3(128, 2), dim3(512), 0, stream>>>(
      ctx, W2, nullptr, HID, 64, nullptr, P);

  reduce_kernel<<<dim3(2048), dim3(256), 0, stream>>>(
      P, P + (size_t)S_LEN * HID, bdense, out, S_LEN * HID / 4);
}

// Round 6
// 572.663 us; speedup vs baseline: 1.6538x; 1.6538x over previous
//
#include <hip/hip_runtime.h>

typedef unsigned short u16;
typedef unsigned int u32;
typedef __attribute__((ext_vector_type(4))) float f32x4;
typedef __attribute__((ext_vector_type(8))) short bf16x8;
typedef __attribute__((ext_vector_type(2))) unsigned int u32x2;

#define S_LEN 2048
#define NHEAD 32
#define HDD 128
#define HID 4096
#define N_QKV 12288
#define KDIM 4096
#define RS 12288  // mixed row stride (elements)

__device__ __forceinline__ u16 f2bf(float f) {
  u32 u = __builtin_bit_cast(u32, f);
  u = (u + 0x7FFFu + ((u >> 16) & 1u)) >> 16;
  return (u16)u;
}
__device__ __forceinline__ float bf2f(u16 h) {
  u32 u = ((u32)h) << 16;
  return __builtin_bit_cast(float, u);
}

__device__ __forceinline__ void gl2lds16(const void* g, void* l) {
  __builtin_amdgcn_global_load_lds(
      (const __attribute__((address_space(1))) u32*)g,
      (__attribute__((address_space(3))) u32*)l, 16, 0, 0);
}

// ---------------- fused fp32 -> bf16 conversion (3 tensors) ---------------
__global__ __launch_bounds__(256) void cvt3_kernel(const float* __restrict__ s0, u16* __restrict__ d0, int n0,
                                                   const float* __restrict__ s1, u16* __restrict__ d1, int n1,
                                                   const float* __restrict__ s2, u16* __restrict__ d2, int n2) {
  int i = blockIdx.x * blockDim.x + threadIdx.x;
  int st = gridDim.x * blockDim.x;
  int ntot = n0 + n1 + n2;
  for (; i < ntot; i += st) {
    const float* s;
    u16* d;
    int j = i;
    if (j < n0) {
      s = s0; d = d0;
    } else if (j < n0 + n1) {
      j -= n0; s = s1; d = d1;
    } else {
      j -= n0 + n1; s = s2; d = d2;
    }
    float4 v = ((const float4*)s)[j];
    u32x2 o;
    o.x = (u32)f2bf(v.x) | ((u32)f2bf(v.y) << 16);
    o.y = (u32)f2bf(v.z) | ((u32)f2bf(v.w) << 16);
    ((u32x2*)d)[j] = o;
  }
}

// ---------------- RoPE tables: cos/sin [S][32] ----------------
__global__ __launch_bounds__(256) void tables_kernel(float* __restrict__ cos_t,
                                                     float* __restrict__ sin_t) {
  int idx = blockIdx.x * blockDim.x + threadIdx.x;
  if (idx >= S_LEN * 32) return;
  int s = idx >> 5, i = idx & 31;
  float invf = expf(-0.28782313662425572f * (float)i);
  float a = (float)s * invf;
  cos_t[idx] = cosf(a);
  sin_t[idx] = sinf(a);
}

// ---------------- 2D RoPE in-place on mixed [s][12288] --------------------
__global__ __launch_bounds__(256) void rope_kernel(u16* __restrict__ mixed,
                                                   const int* __restrict__ pid,
                                                   const float* __restrict__ cos_t,
                                                   const float* __restrict__ sin_t) {
  int idx = blockIdx.x * blockDim.x + threadIdx.x;
  const int total = 2 * NHEAD * S_LEN * 2 * 8;  // 2^21
  if (idx >= total) return;
  int j = idx & 7;
  int half = (idx >> 3) & 1;
  int s = (idx >> 4) & (S_LEN - 1);
  int h = (idx >> 15) & (NHEAD - 1);
  int qk = idx >> 20;
  int i0 = j * 4;
  int p = pid[half * S_LEN + s];
  float4 c4 = *(const float4*)(cos_t + p * 32 + i0);
  float4 s4 = *(const float4*)(sin_t + p * 32 + i0);
  u16* base = mixed + (size_t)s * RS + h * 384 + qk * 128 + half * 64 + i0;
  ushort4 x1v = *(const ushort4*)(base);
  ushort4 x2v = *(const ushort4*)(base + 32);
  float sc = qk ? 1.0f : 0.08838834764831845f;
  ushort4 o1, o2;
  {
    float x1 = bf2f(x1v.x), x2 = bf2f(x2v.x);
    o1.x = f2bf((x1 * c4.x - x2 * s4.x) * sc);
    o2.x = f2bf((x2 * c4.x + x1 * s4.x) * sc);
  }
  {
    float x1 = bf2f(x1v.y), x2 = bf2f(x2v.y);
    o1.y = f2bf((x1 * c4.y - x2 * s4.y) * sc);
    o2.y = f2bf((x2 * c4.y + x1 * s4.y) * sc);
  }
  {
    float x1 = bf2f(x1v.z), x2 = bf2f(x2v.z);
    o1.z = f2bf((x1 * c4.z - x2 * s4.z) * sc);
    o2.z = f2bf((x2 * c4.z + x1 * s4.z) * sc);
  }
  {
    float x1 = bf2f(x1v.w), x2 = bf2f(x2v.w);
    o1.w = f2bf((x1 * c4.w - x2 * s4.w) * sc);
    o2.w = f2bf((x2 * c4.w + x1 * s4.w) * sc);
  }
  *(ushort4*)(base) = o1;
  *(ushort4*)(base + 32) = o2;
}

// ---------------- 256x256 bf16 GEMM, m201-faithful 2-phase/tile -----------
// C = A * B^T (+bias).  A:[M][4096] bf16, B:[N][4096] bf16 (K contiguous).
// BK=32, ring-4 x 32KB LDS (A 16KB | B 16KB per buffer). 512 thr = 8 waves
// (2M x 4N), per-wave 128x64, acc 8x4 f32x4.
// Per K-tile: 2 phases, each {ds_read frags | ISSUE one unit (2 gload_lds) |
//   barrier | setprio(1) 16 MFMA setprio(0) | barrier}.
// Prefetch distance 3 tiles; vmcnt(8) once per tile at ph1 end (certified
// unit has ~5-phase lead > HBM latency; queue never drains below 8 mid-loop).
// Unit layout: paired-row 128B lines, 16B slot ^= (line&7); gload_lds dest
// linear, global SOURCE inverse-swizzled (involution both sides).
// Split-K via blockIdx.y (k0 = y*2048 elems), outf += y*S_LEN*N.
template <int EPI>
__global__ __launch_bounds__(512, 2) void gemm8p(const u16* __restrict__ A,
                                                 const u16* __restrict__ B,
                                                 const float* __restrict__ bias, int N, int NTt,
                                                 u16* __restrict__ outb, float* __restrict__ outf) {
  __shared__ __align__(16) char lds[4][32768];

  const int tid = threadIdx.x;
  const int lane = tid & 63, w = tid >> 6;
  const int l15 = lane & 15, g = lane >> 4;
  const int wm = w >> 2, wn = w & 3;

  // bijective XCD swizzle (gridDim.x = 8*perx, perx = 8*npx), M-fastest
  int perx = gridDim.x >> 3;
  int npx = perx >> 3;
  int x = blockIdx.x & 7, loc = blockIdx.x >> 3;
  int mb = loc & 7, nb = x * npx + (loc >> 3);
  const int bm = mb * 256, bn = nb * 256;

  const u16* Ag = A + (size_t)blockIdx.y * 2048;
  const u16* Bg = B + (size_t)blockIdx.y * 2048;

  f32x4 acc[8][4];
  f32x4 z4 = {0.f, 0.f, 0.f, 0.f};
#pragma unroll
  for (int mi = 0; mi < 8; ++mi)
#pragma unroll
    for (int ni = 0; ni < 4; ++ni) acc[mi][ni] = z4;

  // staging inverse-swizzle: load j covers LDS 16B-slot (j*512+tid) of a unit
  int srow[2], skb[2];
#pragma unroll
  for (int j = 0; j < 2; ++j) {
    int slot = j * 512 + tid;
    int line = slot >> 3;
    int sl = (slot & 7) ^ (line & 7);
    srow[j] = 2 * line + (sl >> 2);
    skb[j] = (sl & 3) * 16;
  }
  const size_t K2 = (size_t)KDIM * 2;
  const char* gA[2];
  const char* gB[2];
#pragma unroll
  for (int j = 0; j < 2; ++j) {
    gA[j] = (const char*)Ag + (size_t)(bm + srow[j]) * K2 + skb[j];
    gB[j] = (const char*)Bg + (size_t)(bn + srow[j]) * K2 + skb[j];
  }
  const int ldst = w * 1024;  // + j*8192; A unit at 0, B unit at 16384

#define ISSUE_A(t)                                             \
  {                                                            \
    char* Lb = lds[(t) & 3];                                   \
    gl2lds16(gA[0] + (size_t)(t) * 64, Lb + ldst);             \
    gl2lds16(gA[1] + (size_t)(t) * 64, Lb + 8192 + ldst);      \
  }
#define ISSUE_B(t)                                             \
  {                                                            \
    char* Lb = lds[(t) & 3] + 16384;                           \
    gl2lds16(gB[0] + (size_t)(t) * 64, Lb + ldst);             \
    gl2lds16(gB[1] + (size_t)(t) * 64, Lb + 8192 + ldst);      \
  }

  // fragment ds_read byte offsets (swizzled), constant across tiles
  int offA[8], offB[4];
#pragma unroll
  for (int mi = 0; mi < 8; ++mi) {
    int r = wm * 128 + mi * 16 + l15;
    int line = r >> 1;
    int sl = (((r & 1) << 2) + g) ^ (line & 7);
    offA[mi] = line * 128 + sl * 16;
  }
#pragma unroll
  for (int ni = 0; ni < 4; ++ni) {
    int r = wn * 64 + ni * 16 + l15;
    int line = r >> 1;
    int sl = (((r & 1) << 2) + g) ^ (line & 7);
    offB[ni] = 16384 + line * 128 + sl * 16;
  }

  // ---- prologue: stage tiles 0,1,2 (12 loads); certify tile0 via vmcnt(8)
  ISSUE_A(0); ISSUE_B(0);
  ISSUE_A(1); ISSUE_B(1);
  ISSUE_A(2); ISSUE_B(2);
  asm volatile("s_waitcnt vmcnt(8)" ::: "memory");
  __builtin_amdgcn_s_barrier();
  asm volatile("" ::: "memory");

  for (int kt = 0; kt < NTt; ++kt) {
    const char* buf = lds[kt & 3];
    const bool pf = (kt + 3) < NTt;
    bf16x8 a[4], a2[4], b[4];
    // ---- ph0: frags (a0-3, b0-3) | ISSUE A(kt+3) | barrier | 16 MFMA | barrier
#pragma unroll
    for (int mi = 0; mi < 4; ++mi) a[mi] = *(const bf16x8*)(buf + offA[mi]);
#pragma unroll
    for (int ni = 0; ni < 4; ++ni) b[ni] = *(const bf16x8*)(buf + offB[ni]);
    if (pf) ISSUE_A(kt + 3);
    asm volatile("" ::: "memory");
    __builtin_amdgcn_s_barrier();
    asm volatile("" ::: "memory");
    __builtin_amdgcn_s_setprio(1);
#pragma unroll
    for (int mi = 0; mi < 4; ++mi)
#pragma unroll
      for (int ni = 0; ni < 4; ++ni)
        acc[mi][ni] = __builtin_amdgcn_mfma_f32_16x16x32_bf16(a[mi], b[ni], acc[mi][ni], 0, 0, 0);
    __builtin_amdgcn_s_setprio(0);
    asm volatile("" ::: "memory");
    __builtin_amdgcn_s_barrier();
    asm volatile("" ::: "memory");
    // ---- ph1: frags (a4-7) | ISSUE B(kt+3) | vmcnt | barrier | 16 MFMA | barrier
#pragma unroll
    for (int mi = 0; mi < 4; ++mi) a2[mi] = *(const bf16x8*)(buf + offA[4 + mi]);
    if (pf) ISSUE_B(kt + 3);
    if (kt < NTt - 3) {
      asm volatile("s_waitcnt vmcnt(8)" ::: "memory");
    } else if (kt == NTt - 3) {
      asm volatile("s_waitcnt vmcnt(4)" ::: "memory");
    } else if (kt == NTt - 2) {
      asm volatile("s_waitcnt vmcnt(0)" ::: "memory");
    }
    __builtin_amdgcn_s_barrier();
    asm volatile("" ::: "memory");
    __builtin_amdgcn_s_setprio(1);
#pragma unroll
    for (int mi = 0; mi < 4; ++mi)
#pragma unroll
      for (int ni = 0; ni < 4; ++ni)
        acc[4 + mi][ni] = __builtin_amdgcn_mfma_f32_16x16x32_bf16(a2[mi], b[ni], acc[4 + mi][ni], 0, 0, 0);
    __builtin_amdgcn_s_setprio(0);
    asm volatile("" ::: "memory");
    __builtin_amdgcn_s_barrier();
    asm volatile("" ::: "memory");
  }
#undef ISSUE_A
#undef ISSUE_B

  // ---- epilogue: D row(M) = 4*g + reg, col(N) = l15
  float* of = outf ? outf + (size_t)blockIdx.y * S_LEN * N : nullptr;
#pragma unroll
  for (int ni = 0; ni < 4; ++ni) {
    int n = bn + wn * 64 + ni * 16 + l15;
    if (EPI == 0) {
      float bv = bias[n];
#pragma unroll
      for (int mi = 0; mi < 8; ++mi) {
        int m0 = bm + wm * 128 + mi * 16 + 4 * g;
#pragma unroll
        for (int rr = 0; rr < 4; ++rr)
          outb[(size_t)(m0 + rr) * N + n] = f2bf(acc[mi][ni][rr] + bv);
      }
    } else {
#pragma unroll
      for (int mi = 0; mi < 8; ++mi) {
        int m0 = bm + wm * 128 + mi * 16 + 4 * g;
#pragma unroll
        for (int rr = 0; rr < 4; ++rr) of[(size_t)(m0 + rr) * N + n] = acc[mi][ni][rr];
      }
    }
  }
}

// ---------------- split-K reduce: out = P0 + P1 + bias --------------------
__global__ __launch_bounds__(256) void reduce_kernel(const float* __restrict__ P0,
                                                     const float* __restrict__ P1,
                                                     const float* __restrict__ bias,
                                                     float* __restrict__ out, int n4) {
  int i = blockIdx.x * blockDim.x + threadIdx.x;
  int st = gridDim.x * blockDim.x;
  for (; i < n4; i += st) {
    float4 a = ((const float4*)P0)[i];
    float4 b = ((const float4*)P1)[i];
    float4 bv = *(const float4*)(bias + ((i * 4) & (HID - 1)));
    float4 o;
    o.x = a.x + b.x + bv.x;
    o.y = a.y + b.y + bv.y;
    o.z = a.z + b.z + bv.z;
    o.w = a.w + b.w + bv.w;
    ((float4*)out)[i] = o;
  }
}

// ---------------- flash attention (reads mixed layout) --------------------
__global__ __launch_bounds__(256) void attn_kernel(const u16* __restrict__ mixed,
                                                   u16* __restrict__ ctx) {
  __shared__ __align__(16) u16 Ksh[32 * 136];
  __shared__ __align__(16) u16 Vsh[128 * 32];
  __shared__ __align__(16) u16 Pt[4][16 * 40];

  int tid = threadIdx.x;
  int lane = tid & 63, w = tid >> 6;
  int lane15 = lane & 15, g = lane >> 4;
  int h = blockIdx.y;
  int qbase = blockIdx.x * 64;
  int qrow = qbase + w * 16 + lane15;

  const u16* qp = mixed + (size_t)h * 384;
  const u16* kp = mixed + (size_t)h * 384 + 128;
  const u16* vp = mixed + (size_t)h * 384 + 256;

  bf16x8 qf[4];
  const u16* qptr = qp + (size_t)qrow * RS + g * 8;
#pragma unroll
  for (int d0 = 0; d0 < 4; ++d0) qf[d0] = *(const bf16x8*)(qptr + d0 * 32);

  f32x4 pv[8];
  f32x4 z4 = {0.f, 0.f, 0.f, 0.f};
#pragma unroll
  for (int db = 0; db < 8; ++db) pv[db] = z4;
  float m_run = -1e30f, l_run = 0.0f;

  int krow = tid >> 3, kc = (tid & 7) * 16;
  int a_ = tid & 15, b_ = tid >> 4;
  int ntiles = (qbase >> 5) + 2;

  for (int t = 0; t < ntiles; ++t) {
    int kb0 = t * 32;
    __syncthreads();
    {
      const bf16x8* src = (const bf16x8*)(kp + (size_t)(kb0 + krow) * RS + kc);
      bf16x8 x0 = src[0], x1 = src[1];
      *(bf16x8*)(Ksh + krow * 136 + kc) = x0;
      *(bf16x8*)(Ksh + krow * 136 + kc + 8) = x1;
      int k0 = 2 * a_, d0 = 8 * b_;
      bf16x8 r0 = *(const bf16x8*)(vp + (size_t)(kb0 + k0) * RS + d0);
      bf16x8 r1 = *(const bf16x8*)(vp + (size_t)(kb0 + k0 + 1) * RS + d0);
#pragma unroll
      for (int jj = 0; jj < 8; ++jj) {
        int d = d0 + jj;
        u32 val = (u32)(u16)r0[jj] | ((u32)(u16)r1[jj] << 16);
        *(u32*)(Vsh + d * 32 + (((k0 >> 3) ^ (d & 3)) << 3) + (k0 & 7)) = val;
      }
    }
    __syncthreads();

    f32x4 sa0 = z4, sa1 = z4;
#pragma unroll
    for (int d0 = 0; d0 < 4; ++d0) {
      bf16x8 k0f = *(const bf16x8*)(Ksh + lane15 * 136 + d0 * 32 + g * 8);
      bf16x8 k1f = *(const bf16x8*)(Ksh + (16 + lane15) * 136 + d0 * 32 + g * 8);
      sa0 = __builtin_amdgcn_mfma_f32_16x16x32_bf16(k0f, qf[d0], sa0, 0, 0, 0);
      sa1 = __builtin_amdgcn_mfma_f32_16x16x32_bf16(k1f, qf[d0], sa1, 0, 0, 0);
    }
    float s[8];
#pragma unroll
    for (int rr = 0; rr < 4; ++rr) {
      int kg0 = kb0 + 4 * g + rr;
      int kg1 = kb0 + 16 + 4 * g + rr;
      s[rr] = (kg0 > qrow) ? -1e30f : sa0[rr];
      s[4 + rr] = (kg1 > qrow) ? -1e30f : sa1[rr];
    }
    float mx = s[0];
#pragma unroll
    for (int i = 1; i < 8; ++i) mx = fmaxf(mx, s[i]);
    mx = fmaxf(mx, __shfl_xor(mx, 16));
    mx = fmaxf(mx, __shfl_xor(mx, 32));
    float mnew = fmaxf(m_run, mx);
    float fac = exp2f((m_run - mnew) * 1.4426950408889634f);
    float p[8], psum = 0.f;
#pragma unroll
    for (int i = 0; i < 8; ++i) {
      p[i] = exp2f((s[i] - mnew) * 1.4426950408889634f);
      psum += p[i];
    }
    psum += __shfl_xor(psum, 16);
    psum += __shfl_xor(psum, 32);
    l_run = l_run * fac + psum;
    m_run = mnew;
#pragma unroll
    for (int db = 0; db < 8; ++db) pv[db] *= fac;

    u32 w0 = (u32)f2bf(p[0]) | ((u32)f2bf(p[1]) << 16);
    u32 w1 = (u32)f2bf(p[2]) | ((u32)f2bf(p[3]) << 16);
    u32 w2 = (u32)f2bf(p[4]) | ((u32)f2bf(p[5]) << 16);
    u32 w3 = (u32)f2bf(p[6]) | ((u32)f2bf(p[7]) << 16);
    u32x2 pa, pb;
    pa.x = w0; pa.y = w1; pb.x = w2; pb.y = w3;
    *(u32x2*)(&Pt[w][lane15 * 40 + 4 * g]) = pa;
    *(u32x2*)(&Pt[w][lane15 * 40 + 16 + 4 * g]) = pb;
    asm volatile("s_waitcnt lgkmcnt(0)" ::: "memory");
    bf16x8 pfrag = *(const bf16x8*)(&Pt[w][lane15 * 40 + 8 * g]);

#pragma unroll
    for (int db = 0; db < 8; ++db) {
      int d = db * 16 + lane15;
      bf16x8 vf = *(const bf16x8*)(Vsh + d * 32 + ((g ^ (d & 3)) << 3));
      pv[db] = __builtin_amdgcn_mfma_f32_16x16x32_bf16(vf, pfrag, pv[db], 0, 0, 0);
    }
  }

  float inv = 1.0f / l_run;
#pragma unroll
  for (int db = 0; db < 8; ++db) {
    ushort4 o;
    o.x = f2bf(pv[db][0] * inv);
    o.y = f2bf(pv[db][1] * inv);
    o.z = f2bf(pv[db][2] * inv);
    o.w = f2bf(pv[db][3] * inv);
    *(ushort4*)(ctx + (size_t)qrow * HID + h * HDD + db * 16 + 4 * g) = o;
  }
}

// ---------------- launcher -------------------------------------------------
extern "C" void kernel_launch(void* const* d_in, const int* in_sizes, int n_in,
                              void* d_out, int out_size, void* d_ws, size_t ws_size,
                              hipStream_t stream) {
  const float* hidden = (const float*)d_in[0];
  const int* pid = (const int*)d_in[1];
  const float* wqkv = (const float*)d_in[3];
  const float* bqkv = (const float*)d_in[4];
  const float* wdense = (const float*)d_in[5];
  const float* bdense = (const float*)d_in[6];
  float* out = (float*)d_out;

  char* ws = (char*)d_ws;
  u16* W1 = (u16*)ws;                        // [12288][4096] bf16 (dead after QKV)
  u16* W2 = (u16*)(ws + 100663296);          // [4096][4096] bf16
  u16* X = (u16*)(ws + 134217728);           // [2048][4096] bf16
  u16* mixed = (u16*)(ws + 150994944);       // [2048][12288] bf16
  u16* ctx = (u16*)(ws + 201326592);         // [2048][4096] bf16
  float* cos_t = (float*)(ws + 218103808);
  float* sin_t = (float*)(ws + 218365952);
  float* P = (float*)ws;                     // split-K partials reuse W1 region

  cvt3_kernel<<<dim3(2048), dim3(256), 0, stream>>>(
      wqkv, W1, N_QKV * KDIM / 4, wdense, W2, HID * KDIM / 4, hidden, X, S_LEN * HID / 4);
  tables_kernel<<<dim3(256), dim3(256), 0, stream>>>(cos_t, sin_t);

  // QKV: 8 M x 48 N = 384 blocks, NTt = 128 (full K, BK=32)
  gemm8p<0><<<dim3(384), dim3(512), 0, stream>>>(
      X, W1, bqkv, N_QKV, 128, mixed, nullptr);

  rope_kernel<<<dim3(8192), dim3(256), 0, stream>>>(mixed, pid, cos_t, sin_t);

  attn_kernel<<<dim3(S_LEN / 64, NHEAD), dim3(256), 0, stream>>>(mixed, ctx);

  // dense: split-K x2 in ONE launch (blockIdx.y = k-half), 256 blocks
  gemm8p<1><<<dim3(128, 2), dim3(512), 0, stream>>>(
      ctx, W2, nullptr, HID, 64, nullptr, P);

  reduce_kernel<<<dim3(2048), dim3(256), 0, stream>>>(
      P, P + (size_t)S_LEN * HID, bdense, out, S_LEN * HID / 4);
}

// Round 7
// 540.538 us; speedup vs baseline: 1.7521x; 1.0594x over previous
//
#include <hip/hip_runtime.h>

typedef unsigned short u16;
typedef unsigned int u32;
typedef __attribute__((ext_vector_type(4))) float f32x4;
typedef __attribute__((ext_vector_type(8))) short bf16x8;
typedef __attribute__((ext_vector_type(2))) unsigned int u32x2;

#define S_LEN 2048
#define NHEAD 32
#define HDD 128
#define HID 4096
#define N_QKV 12288
#define KDIM 4096
#define RS 12288  // mixed row stride (elements)

__device__ __forceinline__ u16 f2bf(float f) {
  u32 u = __builtin_bit_cast(u32, f);
  u = (u + 0x7FFFu + ((u >> 16) & 1u)) >> 16;
  return (u16)u;
}
__device__ __forceinline__ float bf2f(u16 h) {
  u32 u = ((u32)h) << 16;
  return __builtin_bit_cast(float, u);
}

__device__ __forceinline__ void gl2lds16(const void* g, void* l) {
  __builtin_amdgcn_global_load_lds(
      (const __attribute__((address_space(1))) u32*)g,
      (__attribute__((address_space(3))) u32*)l, 16, 0, 0);
}

#define FULL_BAR()                          \
  {                                         \
    asm volatile("" ::: "memory");          \
    __builtin_amdgcn_s_barrier();           \
    asm volatile("" ::: "memory");          \
  }

// ---------------- fused fp32 -> bf16 conversion (3 tensors) ---------------
__global__ __launch_bounds__(256) void cvt3_kernel(const float* __restrict__ s0, u16* __restrict__ d0, int n0,
                                                   const float* __restrict__ s1, u16* __restrict__ d1, int n1,
                                                   const float* __restrict__ s2, u16* __restrict__ d2, int n2) {
  int i = blockIdx.x * blockDim.x + threadIdx.x;
  int st = gridDim.x * blockDim.x;
  int ntot = n0 + n1 + n2;
  for (; i < ntot; i += st) {
    const float* s;
    u16* d;
    int j = i;
    if (j < n0) {
      s = s0; d = d0;
    } else if (j < n0 + n1) {
      j -= n0; s = s1; d = d1;
    } else {
      j -= n0 + n1; s = s2; d = d2;
    }
    float4 v = ((const float4*)s)[j];
    u32x2 o;
    o.x = (u32)f2bf(v.x) | ((u32)f2bf(v.y) << 16);
    o.y = (u32)f2bf(v.z) | ((u32)f2bf(v.w) << 16);
    ((u32x2*)d)[j] = o;
  }
}

// ---------------- RoPE tables: cos/sin [S][32] ----------------
__global__ __launch_bounds__(256) void tables_kernel(float* __restrict__ cos_t,
                                                     float* __restrict__ sin_t) {
  int idx = blockIdx.x * blockDim.x + threadIdx.x;
  if (idx >= S_LEN * 32) return;
  int s = idx >> 5, i = idx & 31;
  float invf = expf(-0.28782313662425572f * (float)i);
  float a = (float)s * invf;
  cos_t[idx] = cosf(a);
  sin_t[idx] = sinf(a);
}

// ---------------- 2D RoPE in-place on mixed [s][12288] --------------------
__global__ __launch_bounds__(256) void rope_kernel(u16* __restrict__ mixed,
                                                   const int* __restrict__ pid,
                                                   const float* __restrict__ cos_t,
                                                   const float* __restrict__ sin_t) {
  int idx = blockIdx.x * blockDim.x + threadIdx.x;
  const int total = 2 * NHEAD * S_LEN * 2 * 8;  // 2^21
  if (idx >= total) return;
  int j = idx & 7;
  int half = (idx >> 3) & 1;
  int s = (idx >> 4) & (S_LEN - 1);
  int h = (idx >> 15) & (NHEAD - 1);
  int qk = idx >> 20;
  int i0 = j * 4;
  int p = pid[half * S_LEN + s];
  float4 c4 = *(const float4*)(cos_t + p * 32 + i0);
  float4 s4 = *(const float4*)(sin_t + p * 32 + i0);
  u16* base = mixed + (size_t)s * RS + h * 384 + qk * 128 + half * 64 + i0;
  ushort4 x1v = *(const ushort4*)(base);
  ushort4 x2v = *(const ushort4*)(base + 32);
  float sc = qk ? 1.0f : 0.08838834764831845f;
  ushort4 o1, o2;
  {
    float x1 = bf2f(x1v.x), x2 = bf2f(x2v.x);
    o1.x = f2bf((x1 * c4.x - x2 * s4.x) * sc);
    o2.x = f2bf((x2 * c4.x + x1 * s4.x) * sc);
  }
  {
    float x1 = bf2f(x1v.y), x2 = bf2f(x2v.y);
    o1.y = f2bf((x1 * c4.y - x2 * s4.y) * sc);
    o2.y = f2bf((x2 * c4.y + x1 * s4.y) * sc);
  }
  {
    float x1 = bf2f(x1v.z), x2 = bf2f(x2v.z);
    o1.z = f2bf((x1 * c4.z - x2 * s4.z) * sc);
    o2.z = f2bf((x2 * c4.z + x1 * s4.z) * sc);
  }
  {
    float x1 = bf2f(x1v.w), x2 = bf2f(x2v.w);
    o1.w = f2bf((x1 * c4.w - x2 * s4.w) * sc);
    o2.w = f2bf((x2 * c4.w + x1 * s4.w) * sc);
  }
  *(ushort4*)(base) = o1;
  *(ushort4*)(base + 32) = o2;
}

// ---------------- 256 x (NI*64) bf16 GEMM, BK=64, R4 schedule -------------
// C = A * B^T (+bias).  A:[M][4096] bf16, B:[N][4096] bf16 (K contiguous).
// 512 thr = 8 waves (2M x 4N), per-wave 128 x NI*16, BK=64 (2 kk-halves).
// LDS buffer = A0(16K) | A1(16K) | B(2 kk-subunits, NI*4K each); ring-2.
// Per tile 4 phases {reads | ISSUE one unit | (vmcnt) | BAR | 12-16 MFMA}:
//   ph0: a_kk0[0-3]+b_kk0 | ISSUE A0(kt+1)
//   ph1: a_kk0[4-7]       | ISSUE B(kt+1) | vmcnt(2+NI) -> A1(kt) certified
//   ph2: a_kk1[0-3]+b_kk1 | ISSUE A1(kt+1)
//   ph3: a_kk1[4-7]       | vmcnt(2) -> A0'(kt+1)+B'(kt+1) certified
// Queue never drains below 2 mid-loop (T4). All tiles use the proven
// paired-row swizzle (line=row>>1, slot ^= line&7): 0 bank conflicts.
// Split-K via blockIdx.y (k0 = y*2048 elems), outf += y*S_LEN*N.
template <int NI, int EPI>
__global__ __launch_bounds__(512, 2) void gemmK(const u16* __restrict__ A,
                                                const u16* __restrict__ B,
                                                const float* __restrict__ bias, int N, int NTt,
                                                u16* __restrict__ outb, float* __restrict__ outf) {
  constexpr int BN = NI * 64;
  constexpr int BSUB = NI * 4096;          // bytes per B kk-subunit
  constexpr int BUFSZ = 32768 + 2 * BSUB;  // 57344 (NI=3) / 65536 (NI=4)
  __shared__ __align__(16) char lds[2][BUFSZ];

  const int tid = threadIdx.x;
  const int lane = tid & 63, w = tid >> 6;
  const int l15 = lane & 15, g = lane >> 4;
  const int wm = w >> 2, wn = w & 3;

  // bijective XCD swizzle (gridDim.x = 8*perx, perx = 8*npx), M-fastest
  int perx = gridDim.x >> 3;
  int npx = perx >> 3;
  int x = blockIdx.x & 7, loc = blockIdx.x >> 3;
  int mb = loc & 7, nb = x * npx + (loc >> 3);
  const int bm = mb * 256, bn = nb * BN;

  const u16* Ag = A + (size_t)blockIdx.y * 2048;
  const u16* Bg = B + (size_t)blockIdx.y * 2048;

  f32x4 acc[8][NI];
  f32x4 z4 = {0.f, 0.f, 0.f, 0.f};
#pragma unroll
  for (int mi = 0; mi < 8; ++mi)
#pragma unroll
    for (int ni = 0; ni < NI; ++ni) acc[mi][ni] = z4;

  const size_t K2 = (size_t)KDIM * 2;

  // ---- A staging map (per kk-subunit: 256 rows x 64B, paired-row swizzle)
  const char* gA[2];
#pragma unroll
  for (int j = 0; j < 2; ++j) {
    int slot = j * 512 + tid;
    int line = slot >> 3;
    int sl = (slot & 7) ^ (line & 7);
    int row = 2 * line + (sl >> 2);
    int colb = (sl & 3) * 16;
    gA[j] = (const char*)Ag + (size_t)(bm + row) * K2 + colb;
  }
  // ---- B staging map (2 kk-subunits of NI*64 rows x 64B, same swizzle)
  const char* gB[NI];
#pragma unroll
  for (int j = 0; j < NI; ++j) {
    int n_ = j * 512 + tid;
    int kkj = (n_ >= NI * 256) ? 1 : 0;
    int m_ = n_ - kkj * NI * 256;
    int line = m_ >> 3;
    int sl = (m_ & 7) ^ (line & 7);
    int row = 2 * line + (sl >> 2);
    int colb = (sl & 3) * 16;
    gB[j] = (const char*)Bg + (size_t)(bn + row) * K2 + kkj * 64 + colb;
  }
  const int ldst = w * 1024;

#define ISSUE_A(t, kk)                                                        \
  {                                                                           \
    char* Lb = lds[(t) & 1] + (kk) * 16384;                                   \
    gl2lds16(gA[0] + (size_t)(t) * 128 + (kk) * 64, Lb + ldst);               \
    gl2lds16(gA[1] + (size_t)(t) * 128 + (kk) * 64, Lb + 8192 + ldst);        \
  }
#define ISSUE_B(t)                                                            \
  {                                                                           \
    char* Lb = lds[(t) & 1] + 32768;                                          \
    _Pragma("unroll")                                                         \
    for (int j = 0; j < NI; ++j)                                              \
      gl2lds16(gB[j] + (size_t)(t) * 128, Lb + j * 8192 + ldst);              \
  }

  // ---- fragment ds_read byte offsets (paired-row swizzle)
  int offA[8], offB[2][NI];
#pragma unroll
  for (int mi = 0; mi < 8; ++mi) {
    int r = wm * 128 + mi * 16 + l15;
    int line = r >> 1;
    int sl = (((r & 1) << 2) + g) ^ (line & 7);
    offA[mi] = line * 128 + sl * 16;
  }
#pragma unroll
  for (int kk = 0; kk < 2; ++kk)
#pragma unroll
    for (int ni = 0; ni < NI; ++ni) {
      int r = wn * (NI * 16) + ni * 16 + l15;
      int line = r >> 1;
      int sl = (((r & 1) << 2) + g) ^ (line & 7);
      offB[kk][ni] = 32768 + kk * BSUB + line * 128 + sl * 16;
    }

  // ---- prologue: stage tile 0 fully, drain, barrier
  ISSUE_A(0, 0);
  ISSUE_B(0);
  ISSUE_A(0, 1);
  asm volatile("s_waitcnt vmcnt(0)" ::: "memory");
  FULL_BAR();

  for (int kt = 0; kt < NTt; ++kt) {
    const char* buf = lds[kt & 1];
    const bool pf = (kt + 1) < NTt;
    bf16x8 a[4], b[NI];
    // ---- ph0: kk0, mi 0-3 (+ b_kk0)
#pragma unroll
    for (int mi = 0; mi < 4; ++mi) a[mi] = *(const bf16x8*)(buf + offA[mi]);
#pragma unroll
    for (int ni = 0; ni < NI; ++ni) b[ni] = *(const bf16x8*)(buf + offB[0][ni]);
    if (pf) ISSUE_A(kt + 1, 0);
    FULL_BAR();
    __builtin_amdgcn_s_setprio(1);
#pragma unroll
    for (int mi = 0; mi < 4; ++mi)
#pragma unroll
      for (int ni = 0; ni < NI; ++ni)
        acc[mi][ni] = __builtin_amdgcn_mfma_f32_16x16x32_bf16(a[mi], b[ni], acc[mi][ni], 0, 0, 0);
    __builtin_amdgcn_s_setprio(0);
    // ---- ph1: kk0, mi 4-7
#pragma unroll
    for (int mi = 0; mi < 4; ++mi) a[mi] = *(const bf16x8*)(buf + offA[4 + mi]);
    if (pf) ISSUE_B(kt + 1);
    if (pf) {
      if constexpr (NI == 3) {
        asm volatile("s_waitcnt vmcnt(5)" ::: "memory");
      } else {
        asm volatile("s_waitcnt vmcnt(6)" ::: "memory");
      }
    } else {
      asm volatile("s_waitcnt vmcnt(0)" ::: "memory");
    }
    FULL_BAR();
    __builtin_amdgcn_s_setprio(1);
#pragma unroll
    for (int mi = 0; mi < 4; ++mi)
#pragma unroll
      for (int ni = 0; ni < NI; ++ni)
        acc[4 + mi][ni] = __builtin_amdgcn_mfma_f32_16x16x32_bf16(a[mi], b[ni], acc[4 + mi][ni], 0, 0, 0);
    __builtin_amdgcn_s_setprio(0);
    // ---- ph2: kk1, mi 0-3 (+ b_kk1)
#pragma unroll
    for (int mi = 0; mi < 4; ++mi) a[mi] = *(const bf16x8*)(buf + 16384 + offA[mi]);
#pragma unroll
    for (int ni = 0; ni < NI; ++ni) b[ni] = *(const bf16x8*)(buf + offB[1][ni]);
    if (pf) ISSUE_A(kt + 1, 1);
    FULL_BAR();
    __builtin_amdgcn_s_setprio(1);
#pragma unroll
    for (int mi = 0; mi < 4; ++mi)
#pragma unroll
      for (int ni = 0; ni < NI; ++ni)
        acc[mi][ni] = __builtin_amdgcn_mfma_f32_16x16x32_bf16(a[mi], b[ni], acc[mi][ni], 0, 0, 0);
    __builtin_amdgcn_s_setprio(0);
    // ---- ph3: kk1, mi 4-7
#pragma unroll
    for (int mi = 0; mi < 4; ++mi) a[mi] = *(const bf16x8*)(buf + 16384 + offA[4 + mi]);
    if (pf) asm volatile("s_waitcnt vmcnt(2)" ::: "memory");
    FULL_BAR();
    __builtin_amdgcn_s_setprio(1);
#pragma unroll
    for (int mi = 0; mi < 4; ++mi)
#pragma unroll
      for (int ni = 0; ni < NI; ++ni)
        acc[4 + mi][ni] = __builtin_amdgcn_mfma_f32_16x16x32_bf16(a[mi], b[ni], acc[4 + mi][ni], 0, 0, 0);
    __builtin_amdgcn_s_setprio(0);
  }
#undef ISSUE_A
#undef ISSUE_B

  // ---- epilogue: D row(M) = 4*g + reg, col(N) = l15
  float* of = outf ? outf + (size_t)blockIdx.y * S_LEN * N : nullptr;
#pragma unroll
  for (int ni = 0; ni < NI; ++ni) {
    int n = bn + wn * (NI * 16) + ni * 16 + l15;
    if (EPI == 0) {
      float bv = bias[n];
#pragma unroll
      for (int mi = 0; mi < 8; ++mi) {
        int m0 = bm + wm * 128 + mi * 16 + 4 * g;
#pragma unroll
        for (int rr = 0; rr < 4; ++rr)
          outb[(size_t)(m0 + rr) * N + n] = f2bf(acc[mi][ni][rr] + bv);
      }
    } else {
#pragma unroll
      for (int mi = 0; mi < 8; ++mi) {
        int m0 = bm + wm * 128 + mi * 16 + 4 * g;
#pragma unroll
        for (int rr = 0; rr < 4; ++rr) of[(size_t)(m0 + rr) * N + n] = acc[mi][ni][rr];
      }
    }
  }
}

// ---------------- split-K reduce: out = P0 + P1 + bias --------------------
__global__ __launch_bounds__(256) void reduce_kernel(const float* __restrict__ P0,
                                                     const float* __restrict__ P1,
                                                     const float* __restrict__ bias,
                                                     float* __restrict__ out, int n4) {
  int i = blockIdx.x * blockDim.x + threadIdx.x;
  int st = gridDim.x * blockDim.x;
  for (; i < n4; i += st) {
    float4 a = ((const float4*)P0)[i];
    float4 b = ((const float4*)P1)[i];
    float4 bv = *(const float4*)(bias + ((i * 4) & (HID - 1)));
    float4 o;
    o.x = a.x + b.x + bv.x;
    o.y = a.y + b.y + bv.y;
    o.z = a.z + b.z + bv.z;
    o.w = a.w + b.w + bv.w;
    ((float4*)out)[i] = o;
  }
}

// ---------------- flash attention (reads mixed layout) --------------------
__global__ __launch_bounds__(256) void attn_kernel(const u16* __restrict__ mixed,
                                                   u16* __restrict__ ctx) {
  __shared__ __align__(16) u16 Ksh[32 * 136];
  __shared__ __align__(16) u16 Vsh[128 * 32];
  __shared__ __align__(16) u16 Pt[4][16 * 40];

  int tid = threadIdx.x;
  int lane = tid & 63, w = tid >> 6;
  int lane15 = lane & 15, g = lane >> 4;
  int h = blockIdx.y;
  int qbase = blockIdx.x * 64;
  int qrow = qbase + w * 16 + lane15;

  const u16* qp = mixed + (size_t)h * 384;
  const u16* kp = mixed + (size_t)h * 384 + 128;
  const u16* vp = mixed + (size_t)h * 384 + 256;

  bf16x8 qf[4];
  const u16* qptr = qp + (size_t)qrow * RS + g * 8;
#pragma unroll
  for (int d0 = 0; d0 < 4; ++d0) qf[d0] = *(const bf16x8*)(qptr + d0 * 32);

  f32x4 pv[8];
  f32x4 z4 = {0.f, 0.f, 0.f, 0.f};
#pragma unroll
  for (int db = 0; db < 8; ++db) pv[db] = z4;
  float m_run = -1e30f, l_run = 0.0f;

  int krow = tid >> 3, kc = (tid & 7) * 16;
  int a_ = tid & 15, b_ = tid >> 4;
  int ntiles = (qbase >> 5) + 2;

  for (int t = 0; t < ntiles; ++t) {
    int kb0 = t * 32;
    __syncthreads();
    {
      const bf16x8* src = (const bf16x8*)(kp + (size_t)(kb0 + krow) * RS + kc);
      bf16x8 x0 = src[0], x1 = src[1];
      *(bf16x8*)(Ksh + krow * 136 + kc) = x0;
      *(bf16x8*)(Ksh + krow * 136 + kc + 8) = x1;
      int k0 = 2 * a_, d0 = 8 * b_;
      bf16x8 r0 = *(const bf16x8*)(vp + (size_t)(kb0 + k0) * RS + d0);
      bf16x8 r1 = *(const bf16x8*)(vp + (size_t)(kb0 + k0 + 1) * RS + d0);
#pragma unroll
      for (int jj = 0; jj < 8; ++jj) {
        int d = d0 + jj;
        u32 val = (u32)(u16)r0[jj] | ((u32)(u16)r1[jj] << 16);
        *(u32*)(Vsh + d * 32 + (((k0 >> 3) ^ (d & 3)) << 3) + (k0 & 7)) = val;
      }
    }
    __syncthreads();

    f32x4 sa0 = z4, sa1 = z4;
#pragma unroll
    for (int d0 = 0; d0 < 4; ++d0) {
      bf16x8 k0f = *(const bf16x8*)(Ksh + lane15 * 136 + d0 * 32 + g * 8);
      bf16x8 k1f = *(const bf16x8*)(Ksh + (16 + lane15) * 136 + d0 * 32 + g * 8);
      sa0 = __builtin_amdgcn_mfma_f32_16x16x32_bf16(k0f, qf[d0], sa0, 0, 0, 0);
      sa1 = __builtin_amdgcn_mfma_f32_16x16x32_bf16(k1f, qf[d0], sa1, 0, 0, 0);
    }
    float s[8];
#pragma unroll
    for (int rr = 0; rr < 4; ++rr) {
      int kg0 = kb0 + 4 * g + rr;
      int kg1 = kb0 + 16 + 4 * g + rr;
      s[rr] = (kg0 > qrow) ? -1e30f : sa0[rr];
      s[4 + rr] = (kg1 > qrow) ? -1e30f : sa1[rr];
    }
    float mx = s[0];
#pragma unroll
    for (int i = 1; i < 8; ++i) mx = fmaxf(mx, s[i]);
    mx = fmaxf(mx, __shfl_xor(mx, 16));
    mx = fmaxf(mx, __shfl_xor(mx, 32));
    float mnew = fmaxf(m_run, mx);
    float fac = exp2f((m_run - mnew) * 1.4426950408889634f);
    float p[8], psum = 0.f;
#pragma unroll
    for (int i = 0; i < 8; ++i) {
      p[i] = exp2f((s[i] - mnew) * 1.4426950408889634f);
      psum += p[i];
    }
    psum += __shfl_xor(psum, 16);
    psum += __shfl_xor(psum, 32);
    l_run = l_run * fac + psum;
    m_run = mnew;
#pragma unroll
    for (int db = 0; db < 8; ++db) pv[db] *= fac;

    u32 w0 = (u32)f2bf(p[0]) | ((u32)f2bf(p[1]) << 16);
    u32 w1 = (u32)f2bf(p[2]) | ((u32)f2bf(p[3]) << 16);
    u32 w2 = (u32)f2bf(p[4]) | ((u32)f2bf(p[5]) << 16);
    u32 w3 = (u32)f2bf(p[6]) | ((u32)f2bf(p[7]) << 16);
    u32x2 pa, pb;
    pa.x = w0; pa.y = w1; pb.x = w2; pb.y = w3;
    *(u32x2*)(&Pt[w][lane15 * 40 + 4 * g]) = pa;
    *(u32x2*)(&Pt[w][lane15 * 40 + 16 + 4 * g]) = pb;
    asm volatile("s_waitcnt lgkmcnt(0)" ::: "memory");
    bf16x8 pfrag = *(const bf16x8*)(&Pt[w][lane15 * 40 + 8 * g]);

#pragma unroll
    for (int db = 0; db < 8; ++db) {
      int d = db * 16 + lane15;
      bf16x8 vf = *(const bf16x8*)(Vsh + d * 32 + ((g ^ (d & 3)) << 3));
      pv[db] = __builtin_amdgcn_mfma_f32_16x16x32_bf16(vf, pfrag, pv[db], 0, 0, 0);
    }
  }

  float inv = 1.0f / l_run;
#pragma unroll
  for (int db = 0; db < 8; ++db) {
    ushort4 o;
    o.x = f2bf(pv[db][0] * inv);
    o.y = f2bf(pv[db][1] * inv);
    o.z = f2bf(pv[db][2] * inv);
    o.w = f2bf(pv[db][3] * inv);
    *(ushort4*)(ctx + (size_t)qrow * HID + h * HDD + db * 16 + 4 * g) = o;
  }
}

// ---------------- launcher -------------------------------------------------
extern "C" void kernel_launch(void* const* d_in, const int* in_sizes, int n_in,
                              void* d_out, int out_size, void* d_ws, size_t ws_size,
                              hipStream_t stream) {
  const float* hidden = (const float*)d_in[0];
  const int* pid = (const int*)d_in[1];
  const float* wqkv = (const float*)d_in[3];
  const float* bqkv = (const float*)d_in[4];
  const float* wdense = (const float*)d_in[5];
  const float* bdense = (const float*)d_in[6];
  float* out = (float*)d_out;

  char* ws = (char*)d_ws;
  u16* W1 = (u16*)ws;                        // [12288][4096] bf16 (dead after QKV)
  u16* W2 = (u16*)(ws + 100663296);          // [4096][4096] bf16
  u16* X = (u16*)(ws + 134217728);           // [2048][4096] bf16
  u16* mixed = (u16*)(ws + 150994944);       // [2048][12288] bf16
  u16* ctx = (u16*)(ws + 201326592);         // [2048][4096] bf16
  float* cos_t = (float*)(ws + 218103808);
  float* sin_t = (float*)(ws + 218365952);
  float* P = (float*)ws;                     // split-K partials reuse W1 region

  cvt3_kernel<<<dim3(2048), dim3(256), 0, stream>>>(
      wqkv, W1, N_QKV * KDIM / 4, wdense, W2, HID * KDIM / 4, hidden, X, S_LEN * HID / 4);
  tables_kernel<<<dim3(256), dim3(256), 0, stream>>>(cos_t, sin_t);

  // QKV: BN=192 -> 8 M x 64 N = 512 blocks = 2.00 exact rounds
  gemmK<3, 0><<<dim3(512), dim3(512), 0, stream>>>(
      X, W1, bqkv, N_QKV, 64, mixed, nullptr);

  rope_kernel<<<dim3(8192), dim3(256), 0, stream>>>(mixed, pid, cos_t, sin_t);

  attn_kernel<<<dim3(S_LEN / 64, NHEAD), dim3(256), 0, stream>>>(mixed, ctx);

  // dense: BN=256, split-K x2 (blockIdx.y), 256 blocks = 1.00 exact round
  gemmK<4, 1><<<dim3(128, 2), dim3(512), 0, stream>>>(
      ctx, W2, nullptr, HID, 32, nullptr, P);

  reduce_kernel<<<dim3(2048), dim3(256), 0, stream>>>(
      P, P + (size_t)S_LEN * HID, bdense, out, S_LEN * HID / 4);
}

// Round 8
// 497.783 us; speedup vs baseline: 1.9025x; 1.0859x over previous
//
#include <hip/hip_runtime.h>

typedef unsigned short u16;
typedef unsigned int u32;
typedef __attribute__((ext_vector_type(4))) float f32x4;
typedef __attribute__((ext_vector_type(8))) short bf16x8;
typedef __attribute__((ext_vector_type(2))) unsigned int u32x2;

#define S_LEN 2048
#define NHEAD 32
#define HDD 128
#define HID 4096
#define N_QKV 12288
#define KDIM 4096
#define RS 12288  // mixed row stride (elements)

__device__ __forceinline__ u16 f2bf(float f) {
  u32 u = __builtin_bit_cast(u32, f);
  u = (u + 0x7FFFu + ((u >> 16) & 1u)) >> 16;
  return (u16)u;
}
__device__ __forceinline__ float bf2f(u16 h) {
  u32 u = ((u32)h) << 16;
  return __builtin_bit_cast(float, u);
}

__device__ __forceinline__ void gl2lds16(const void* g, void* l) {
  __builtin_amdgcn_global_load_lds(
      (const __attribute__((address_space(1))) u32*)g,
      (__attribute__((address_space(3))) u32*)l, 16, 0, 0);
}

#define FULL_BAR()                          \
  {                                         \
    asm volatile("" ::: "memory");          \
    __builtin_amdgcn_s_barrier();           \
    asm volatile("" ::: "memory");          \
  }

// ---------------- fused fp32 -> bf16 conversion (3 tensors) ---------------
__global__ __launch_bounds__(256) void cvt3_kernel(const float* __restrict__ s0, u16* __restrict__ d0, int n0,
                                                   const float* __restrict__ s1, u16* __restrict__ d1, int n1,
                                                   const float* __restrict__ s2, u16* __restrict__ d2, int n2) {
  int i = blockIdx.x * blockDim.x + threadIdx.x;
  int st = gridDim.x * blockDim.x;
  int ntot = n0 + n1 + n2;
  for (; i < ntot; i += st) {
    const float* s;
    u16* d;
    int j = i;
    if (j < n0) {
      s = s0; d = d0;
    } else if (j < n0 + n1) {
      j -= n0; s = s1; d = d1;
    } else {
      j -= n0 + n1; s = s2; d = d2;
    }
    float4 v = ((const float4*)s)[j];
    u32x2 o;
    o.x = (u32)f2bf(v.x) | ((u32)f2bf(v.y) << 16);
    o.y = (u32)f2bf(v.z) | ((u32)f2bf(v.w) << 16);
    ((u32x2*)d)[j] = o;
  }
}

// ---------------- RoPE tables: cos/sin [S][32] ----------------
__global__ __launch_bounds__(256) void tables_kernel(float* __restrict__ cos_t,
                                                     float* __restrict__ sin_t) {
  int idx = blockIdx.x * blockDim.x + threadIdx.x;
  if (idx >= S_LEN * 32) return;
  int s = idx >> 5, i = idx & 31;
  float invf = expf(-0.28782313662425572f * (float)i);
  float a = (float)s * invf;
  cos_t[idx] = cosf(a);
  sin_t[idx] = sinf(a);
}

// ---------------- 2D RoPE in-place on mixed [s][12288] --------------------
__global__ __launch_bounds__(256) void rope_kernel(u16* __restrict__ mixed,
                                                   const int* __restrict__ pid,
                                                   const float* __restrict__ cos_t,
                                                   const float* __restrict__ sin_t) {
  int idx = blockIdx.x * blockDim.x + threadIdx.x;
  const int total = 2 * NHEAD * S_LEN * 2 * 8;  // 2^21
  if (idx >= total) return;
  int j = idx & 7;
  int half = (idx >> 3) & 1;
  int s = (idx >> 4) & (S_LEN - 1);
  int h = (idx >> 15) & (NHEAD - 1);
  int qk = idx >> 20;
  int i0 = j * 4;
  int p = pid[half * S_LEN + s];
  float4 c4 = *(const float4*)(cos_t + p * 32 + i0);
  float4 s4 = *(const float4*)(sin_t + p * 32 + i0);
  u16* base = mixed + (size_t)s * RS + h * 384 + qk * 128 + half * 64 + i0;
  ushort4 x1v = *(const ushort4*)(base);
  ushort4 x2v = *(const ushort4*)(base + 32);
  float sc = qk ? 1.0f : 0.08838834764831845f;
  ushort4 o1, o2;
  {
    float x1 = bf2f(x1v.x), x2 = bf2f(x2v.x);
    o1.x = f2bf((x1 * c4.x - x2 * s4.x) * sc);
    o2.x = f2bf((x2 * c4.x + x1 * s4.x) * sc);
  }
  {
    float x1 = bf2f(x1v.y), x2 = bf2f(x2v.y);
    o1.y = f2bf((x1 * c4.y - x2 * s4.y) * sc);
    o2.y = f2bf((x2 * c4.y + x1 * s4.y) * sc);
  }
  {
    float x1 = bf2f(x1v.z), x2 = bf2f(x2v.z);
    o1.z = f2bf((x1 * c4.z - x2 * s4.z) * sc);
    o2.z = f2bf((x2 * c4.z + x1 * s4.z) * sc);
  }
  {
    float x1 = bf2f(x1v.w), x2 = bf2f(x2v.w);
    o1.w = f2bf((x1 * c4.w - x2 * s4.w) * sc);
    o2.w = f2bf((x2 * c4.w + x1 * s4.w) * sc);
  }
  *(ushort4*)(base) = o1;
  *(ushort4*)(base + 32) = o2;
}

// ---------------- 256 x (32*NW) bf16 GEMM, BK=64, 4M x 2N waves -----------
// C = A * B^T (+bias).  A:[M][4096] bf16, B:[N][4096] bf16 (K contiguous).
// 512 thr = 8 waves as 4M x 2N; per-wave 64 x 16*NW; acc[4][NW].
// LDS buffer = A0(16K) | A1(16K) | B(2 kk-subunits, BN*64 B each); ring-2.
// Per tile 4 phases {reads | ISSUE | (vmcnt) | BAR | 4*NW/2 MFMA}:
//   ph0: a(kk0)+b(kk0,lo)  | ISSUE A0(kt+1)
//   ph1: b(kk0,hi)         | ISSUE B(kt+1) | vmcnt(2+NLB) -> A1(kt) certified
//   ph2: a(kk1)+b(kk1,lo)  | ISSUE A1(kt+1)
//   ph3: b(kk1,hi)         | vmcnt(2)      -> A0'(kt+1)+B'(kt+1) certified
// Queue never drains below 2 mid-loop. Paired-row swizzle (line=row>>1,
// slot ^= line&7): verified 0 bank conflicts since R3.
template <int NW, int EPI>
__global__ __launch_bounds__(512, 2) void gemmK(const u16* __restrict__ A,
                                                const u16* __restrict__ B,
                                                const float* __restrict__ bias, int N, int NTt,
                                                u16* __restrict__ outb, float* __restrict__ outf) {
  constexpr int BN = 32 * NW;
  constexpr int NLB = NW / 2;              // B staging loads per thread
  constexpr int BSUB = BN * 64;            // bytes per B kk-subunit
  constexpr int BUFSZ = 32768 + 2 * BSUB;
  constexpr int NH2 = NW / 2;
  __shared__ __align__(16) char lds[2][BUFSZ];

  const int tid = threadIdx.x;
  const int lane = tid & 63, w = tid >> 6;
  const int l15 = lane & 15, g = lane >> 4;
  const int wm = w >> 1, wn = w & 1;  // 4M x 2N wave grid

  // bijective XCD swizzle (gridDim.x = 8*perx, perx = 8*npx), M-fastest
  int perx = gridDim.x >> 3;
  int npx = perx >> 3;
  int x = blockIdx.x & 7, loc = blockIdx.x >> 3;
  int mb = loc & 7, nb = x * npx + (loc >> 3);
  const int bm = mb * 256, bn = nb * BN;

  f32x4 acc[4][NW];
  f32x4 z4 = {0.f, 0.f, 0.f, 0.f};
#pragma unroll
  for (int mi = 0; mi < 4; ++mi)
#pragma unroll
    for (int ni = 0; ni < NW; ++ni) acc[mi][ni] = z4;

  const size_t K2 = (size_t)KDIM * 2;

  // ---- A staging map (per kk-subunit: 256 rows x 64B, paired-row swizzle)
  const char* gA[2];
#pragma unroll
  for (int j = 0; j < 2; ++j) {
    int slot = j * 512 + tid;
    int line = slot >> 3;
    int sl = (slot & 7) ^ (line & 7);
    int row = 2 * line + (sl >> 2);
    int colb = (sl & 3) * 16;
    gA[j] = (const char*)A + (size_t)(bm + row) * K2 + colb;
  }
  // ---- B staging map (2 kk-subunits of BN rows x 64B, same swizzle)
  const char* gB[NLB];
#pragma unroll
  for (int j = 0; j < NLB; ++j) {
    int n_ = j * 512 + tid;
    int kkj = (n_ >= 128 * NW) ? 1 : 0;
    int m_ = n_ - kkj * 128 * NW;
    int line = m_ >> 3;
    int sl = (m_ & 7) ^ (line & 7);
    int row = 2 * line + (sl >> 2);
    int colb = (sl & 3) * 16;
    gB[j] = (const char*)B + (size_t)(bn + row) * K2 + kkj * 64 + colb;
  }
  const int ldst = w * 1024;

#define ISSUE_A(t, kk)                                                        \
  {                                                                           \
    char* Lb = lds[(t) & 1] + (kk) * 16384;                                   \
    gl2lds16(gA[0] + (size_t)(t) * 128 + (kk) * 64, Lb + ldst);               \
    gl2lds16(gA[1] + (size_t)(t) * 128 + (kk) * 64, Lb + 8192 + ldst);        \
  }
#define ISSUE_B(t)                                                            \
  {                                                                           \
    char* Lb = lds[(t) & 1] + 32768;                                          \
    _Pragma("unroll")                                                         \
    for (int j = 0; j < NLB; ++j)                                             \
      gl2lds16(gB[j] + (size_t)(t) * 128, Lb + j * 8192 + ldst);              \
  }

  // ---- fragment ds_read byte offsets (paired-row swizzle)
  int offA[4], offB[2][NW];
#pragma unroll
  for (int mi = 0; mi < 4; ++mi) {
    int r = wm * 64 + mi * 16 + l15;
    int line = r >> 1;
    int sl = (((r & 1) << 2) + g) ^ (line & 7);
    offA[mi] = line * 128 + sl * 16;
  }
#pragma unroll
  for (int kk = 0; kk < 2; ++kk)
#pragma unroll
    for (int ni = 0; ni < NW; ++ni) {
      int r = wn * (16 * NW) + ni * 16 + l15;
      int line = r >> 1;
      int sl = (((r & 1) << 2) + g) ^ (line & 7);
      offB[kk][ni] = 32768 + kk * BSUB + line * 128 + sl * 16;
    }

  // ---- prologue: stage tile 0 fully, drain, barrier
  ISSUE_A(0, 0);
  ISSUE_B(0);
  ISSUE_A(0, 1);
  asm volatile("s_waitcnt vmcnt(0)" ::: "memory");
  FULL_BAR();

  for (int kt = 0; kt < NTt; ++kt) {
    const char* buf = lds[kt & 1];
    const bool pf = (kt + 1) < NTt;
    bf16x8 a[4], b[NH2];
    // ---- ph0: kk0, b lo half
#pragma unroll
    for (int mi = 0; mi < 4; ++mi) a[mi] = *(const bf16x8*)(buf + offA[mi]);
#pragma unroll
    for (int ni = 0; ni < NH2; ++ni) b[ni] = *(const bf16x8*)(buf + offB[0][ni]);
    if (pf) ISSUE_A(kt + 1, 0);
    FULL_BAR();
    __builtin_amdgcn_s_setprio(1);
#pragma unroll
    for (int mi = 0; mi < 4; ++mi)
#pragma unroll
      for (int ni = 0; ni < NH2; ++ni)
        acc[mi][ni] = __builtin_amdgcn_mfma_f32_16x16x32_bf16(a[mi], b[ni], acc[mi][ni], 0, 0, 0);
    __builtin_amdgcn_s_setprio(0);
    // ---- ph1: kk0, b hi half
#pragma unroll
    for (int ni = 0; ni < NH2; ++ni) b[ni] = *(const bf16x8*)(buf + offB[0][NH2 + ni]);
    if (pf) ISSUE_B(kt + 1);
    if (pf) {
      asm volatile("s_waitcnt vmcnt(%0)" ::"i"(2 + NLB) : "memory");
    } else {
      asm volatile("s_waitcnt vmcnt(0)" ::: "memory");
    }
    FULL_BAR();
    __builtin_amdgcn_s_setprio(1);
#pragma unroll
    for (int mi = 0; mi < 4; ++mi)
#pragma unroll
      for (int ni = 0; ni < NH2; ++ni)
        acc[mi][NH2 + ni] = __builtin_amdgcn_mfma_f32_16x16x32_bf16(a[mi], b[ni], acc[mi][NH2 + ni], 0, 0, 0);
    __builtin_amdgcn_s_setprio(0);
    // ---- ph2: kk1, b lo half
#pragma unroll
    for (int mi = 0; mi < 4; ++mi) a[mi] = *(const bf16x8*)(buf + 16384 + offA[mi]);
#pragma unroll
    for (int ni = 0; ni < NH2; ++ni) b[ni] = *(const bf16x8*)(buf + offB[1][ni]);
    if (pf) ISSUE_A(kt + 1, 1);
    FULL_BAR();
    __builtin_amdgcn_s_setprio(1);
#pragma unroll
    for (int mi = 0; mi < 4; ++mi)
#pragma unroll
      for (int ni = 0; ni < NH2; ++ni)
        acc[mi][ni] = __builtin_amdgcn_mfma_f32_16x16x32_bf16(a[mi], b[ni], acc[mi][ni], 0, 0, 0);
    __builtin_amdgcn_s_setprio(0);
    // ---- ph3: kk1, b hi half
#pragma unroll
    for (int ni = 0; ni < NH2; ++ni) b[ni] = *(const bf16x8*)(buf + offB[1][NH2 + ni]);
    if (pf) asm volatile("s_waitcnt vmcnt(2)" ::: "memory");
    FULL_BAR();
    __builtin_amdgcn_s_setprio(1);
#pragma unroll
    for (int mi = 0; mi < 4; ++mi)
#pragma unroll
      for (int ni = 0; ni < NH2; ++ni)
        acc[mi][NH2 + ni] = __builtin_amdgcn_mfma_f32_16x16x32_bf16(a[mi], b[ni], acc[mi][NH2 + ni], 0, 0, 0);
    __builtin_amdgcn_s_setprio(0);
  }
#undef ISSUE_A
#undef ISSUE_B

  // ---- epilogue: D row(M) = 4*g + reg, col(N) = l15
#pragma unroll
  for (int ni = 0; ni < NW; ++ni) {
    int n = bn + wn * (16 * NW) + ni * 16 + l15;
    float bv = bias[n];
    if (EPI == 0) {
#pragma unroll
      for (int mi = 0; mi < 4; ++mi) {
        int m0 = bm + wm * 64 + mi * 16 + 4 * g;
#pragma unroll
        for (int rr = 0; rr < 4; ++rr)
          outb[(size_t)(m0 + rr) * N + n] = f2bf(acc[mi][ni][rr] + bv);
      }
    } else {
#pragma unroll
      for (int mi = 0; mi < 4; ++mi) {
        int m0 = bm + wm * 64 + mi * 16 + 4 * g;
#pragma unroll
        for (int rr = 0; rr < 4; ++rr) outf[(size_t)(m0 + rr) * N + n] = acc[mi][ni][rr] + bv;
      }
    }
  }
}

// ---------------- flash attention (balanced block remap) ------------------
// 1024 blocks, 4/CU co-resident. Co-resident set {i, i+256, i+512, i+768}
// gets qb quartet {q, 15-q, 16+q, 31-q}: per-CU causal work is constant
// (132 tiles) instead of worst-case 256 (the 3.7x imbalance of (qb,h) grids).
__global__ __launch_bounds__(256) void attn_kernel(const u16* __restrict__ mixed,
                                                   u16* __restrict__ ctx) {
  __shared__ __align__(16) u16 Ksh[32 * 136];
  __shared__ __align__(16) u16 Vsh[128 * 32];
  __shared__ __align__(16) u16 Pt[4][16 * 40];

  int tid = threadIdx.x;
  int lane = tid & 63, w = tid >> 6;
  int lane15 = lane & 15, g = lane >> 4;

  int i = blockIdx.x;
  int qb_base = i & 7;
  int h = (i >> 3) & 31;
  int quarter = i >> 8;
  int qbi = (quarter == 0) ? qb_base
            : (quarter == 1) ? (15 - qb_base)
            : (quarter == 2) ? (16 + qb_base)
                             : (31 - qb_base);
  int qbase = qbi * 64;
  int qrow = qbase + w * 16 + lane15;

  const u16* qp = mixed + (size_t)h * 384;
  const u16* kp = mixed + (size_t)h * 384 + 128;
  const u16* vp = mixed + (size_t)h * 384 + 256;

  bf16x8 qf[4];
  const u16* qptr = qp + (size_t)qrow * RS + g * 8;
#pragma unroll
  for (int d0 = 0; d0 < 4; ++d0) qf[d0] = *(const bf16x8*)(qptr + d0 * 32);

  f32x4 pv[8];
  f32x4 z4 = {0.f, 0.f, 0.f, 0.f};
#pragma unroll
  for (int db = 0; db < 8; ++db) pv[db] = z4;
  float m_run = -1e30f, l_run = 0.0f;

  int krow = tid >> 3, kc = (tid & 7) * 16;
  int a_ = tid & 15, b_ = tid >> 4;
  int ntiles = (qbase >> 5) + 2;

  for (int t = 0; t < ntiles; ++t) {
    int kb0 = t * 32;
    __syncthreads();
    {
      const bf16x8* src = (const bf16x8*)(kp + (size_t)(kb0 + krow) * RS + kc);
      bf16x8 x0 = src[0], x1 = src[1];
      *(bf16x8*)(Ksh + krow * 136 + kc) = x0;
      *(bf16x8*)(Ksh + krow * 136 + kc + 8) = x1;
      int k0 = 2 * a_, d0 = 8 * b_;
      bf16x8 r0 = *(const bf16x8*)(vp + (size_t)(kb0 + k0) * RS + d0);
      bf16x8 r1 = *(const bf16x8*)(vp + (size_t)(kb0 + k0 + 1) * RS + d0);
#pragma unroll
      for (int jj = 0; jj < 8; ++jj) {
        int d = d0 + jj;
        u32 val = (u32)(u16)r0[jj] | ((u32)(u16)r1[jj] << 16);
        *(u32*)(Vsh + d * 32 + (((k0 >> 3) ^ (d & 3)) << 3) + (k0 & 7)) = val;
      }
    }
    __syncthreads();

    f32x4 sa0 = z4, sa1 = z4;
#pragma unroll
    for (int d0 = 0; d0 < 4; ++d0) {
      bf16x8 k0f = *(const bf16x8*)(Ksh + lane15 * 136 + d0 * 32 + g * 8);
      bf16x8 k1f = *(const bf16x8*)(Ksh + (16 + lane15) * 136 + d0 * 32 + g * 8);
      sa0 = __builtin_amdgcn_mfma_f32_16x16x32_bf16(k0f, qf[d0], sa0, 0, 0, 0);
      sa1 = __builtin_amdgcn_mfma_f32_16x16x32_bf16(k1f, qf[d0], sa1, 0, 0, 0);
    }
    float s[8];
#pragma unroll
    for (int rr = 0; rr < 4; ++rr) {
      int kg0 = kb0 + 4 * g + rr;
      int kg1 = kb0 + 16 + 4 * g + rr;
      s[rr] = (kg0 > qrow) ? -1e30f : sa0[rr];
      s[4 + rr] = (kg1 > qrow) ? -1e30f : sa1[rr];
    }
    float mx = s[0];
#pragma unroll
    for (int i2 = 1; i2 < 8; ++i2) mx = fmaxf(mx, s[i2]);
    mx = fmaxf(mx, __shfl_xor(mx, 16));
    mx = fmaxf(mx, __shfl_xor(mx, 32));
    float mnew = fmaxf(m_run, mx);
    float fac = exp2f((m_run - mnew) * 1.4426950408889634f);
    float p[8], psum = 0.f;
#pragma unroll
    for (int i2 = 0; i2 < 8; ++i2) {
      p[i2] = exp2f((s[i2] - mnew) * 1.4426950408889634f);
      psum += p[i2];
    }
    psum += __shfl_xor(psum, 16);
    psum += __shfl_xor(psum, 32);
    l_run = l_run * fac + psum;
    m_run = mnew;
#pragma unroll
    for (int db = 0; db < 8; ++db) pv[db] *= fac;

    u32 w0 = (u32)f2bf(p[0]) | ((u32)f2bf(p[1]) << 16);
    u32 w1 = (u32)f2bf(p[2]) | ((u32)f2bf(p[3]) << 16);
    u32 w2 = (u32)f2bf(p[4]) | ((u32)f2bf(p[5]) << 16);
    u32 w3 = (u32)f2bf(p[6]) | ((u32)f2bf(p[7]) << 16);
    u32x2 pa, pb;
    pa.x = w0; pa.y = w1; pb.x = w2; pb.y = w3;
    *(u32x2*)(&Pt[w][lane15 * 40 + 4 * g]) = pa;
    *(u32x2*)(&Pt[w][lane15 * 40 + 16 + 4 * g]) = pb;
    asm volatile("s_waitcnt lgkmcnt(0)" ::: "memory");
    bf16x8 pfrag = *(const bf16x8*)(&Pt[w][lane15 * 40 + 8 * g]);

#pragma unroll
    for (int db = 0; db < 8; ++db) {
      int d = db * 16 + lane15;
      bf16x8 vf = *(const bf16x8*)(Vsh + d * 32 + ((g ^ (d & 3)) << 3));
      pv[db] = __builtin_amdgcn_mfma_f32_16x16x32_bf16(vf, pfrag, pv[db], 0, 0, 0);
    }
  }

  float inv = 1.0f / l_run;
#pragma unroll
  for (int db = 0; db < 8; ++db) {
    ushort4 o;
    o.x = f2bf(pv[db][0] * inv);
    o.y = f2bf(pv[db][1] * inv);
    o.z = f2bf(pv[db][2] * inv);
    o.w = f2bf(pv[db][3] * inv);
    *(ushort4*)(ctx + (size_t)qrow * HID + h * HDD + db * 16 + 4 * g) = o;
  }
}

// ---------------- launcher -------------------------------------------------
extern "C" void kernel_launch(void* const* d_in, const int* in_sizes, int n_in,
                              void* d_out, int out_size, void* d_ws, size_t ws_size,
                              hipStream_t stream) {
  const float* hidden = (const float*)d_in[0];
  const int* pid = (const int*)d_in[1];
  const float* wqkv = (const float*)d_in[3];
  const float* bqkv = (const float*)d_in[4];
  const float* wdense = (const float*)d_in[5];
  const float* bdense = (const float*)d_in[6];
  float* out = (float*)d_out;

  char* ws = (char*)d_ws;
  u16* W1 = (u16*)ws;                        // [12288][4096] bf16
  u16* W2 = (u16*)(ws + 100663296);          // [4096][4096] bf16
  u16* X = (u16*)(ws + 134217728);           // [2048][4096] bf16
  u16* mixed = (u16*)(ws + 150994944);       // [2048][12288] bf16
  u16* ctx = (u16*)(ws + 201326592);         // [2048][4096] bf16
  float* cos_t = (float*)(ws + 218103808);
  float* sin_t = (float*)(ws + 218365952);

  cvt3_kernel<<<dim3(2048), dim3(256), 0, stream>>>(
      wqkv, W1, N_QKV * KDIM / 4, wdense, W2, HID * KDIM / 4, hidden, X, S_LEN * HID / 4);
  tables_kernel<<<dim3(256), dim3(256), 0, stream>>>(cos_t, sin_t);

  // QKV: BN=192 -> 8 M x 64 N = 512 blocks = 2.00 exact rounds
  gemmK<6, 0><<<dim3(512), dim3(512), 0, stream>>>(
      X, W1, bqkv, N_QKV, 64, mixed, nullptr);

  rope_kernel<<<dim3(8192), dim3(256), 0, stream>>>(mixed, pid, cos_t, sin_t);

  attn_kernel<<<dim3(1024), dim3(256), 0, stream>>>(mixed, ctx);

  // dense: BN=128 -> 8 M x 32 N = 256 blocks = 1.00 exact round, no split-K
  gemmK<4, 1><<<dim3(256), dim3(512), 0, stream>>>(
      ctx, W2, bdense, HID, 64, nullptr, out);
}